// Round 9
// baseline (82.448 us; speedup 1.0000x reference)
//
#include <hip/hip_runtime.h>
#include <hip/hip_bf16.h>
#include <cstdint>
#include <cstddef>

#define NB 2
#define NPT 20000
#define KNN 17
#define CH 128
#define NT16 (NPT/16)
#define NT32 (NPT/32)
#define EPSV 1e-5f

typedef short short8 __attribute__((ext_vector_type(8)));
typedef float f32x4 __attribute__((ext_vector_type(4)));
typedef float f32x2 __attribute__((ext_vector_type(2)));
typedef unsigned short u16;

__device__ __forceinline__ unsigned cvtpk(float lo, float hi) {
    unsigned r;
    asm("v_cvt_pk_bf16_f32 %0, %1, %2" : "=v"(r) : "v"(lo), "v"(hi));
    return r;
}
__device__ __forceinline__ u16 f2bf1(float x) { return (u16)cvtpk(x, x); }
__device__ __forceinline__ f32x2 pk_fma(f32x2 a, f32x2 b, f32x2 c) {
    f32x2 d;
    asm("v_pk_fma_f32 %0, %1, %2, %3" : "=v"(d) : "v"(a), "v"(b), "v"(c));
    return d;
}
__device__ __forceinline__ f32x2 pk_mul(f32x2 a, f32x2 b) {
    f32x2 d;
    asm("v_pk_mul_f32 %0, %1, %2" : "=v"(d) : "v"(a), "v"(b));
    return d;
}
__device__ __forceinline__ f32x2 bfpair(unsigned w) {
    union { unsigned u; float f; } lo, hi;
    lo.u = w << 16; hi.u = w & 0xffff0000u;
    f32x2 r; r[0] = lo.f; r[1] = hi.f; return r;
}
__device__ __forceinline__ short8 packrow_scaled(const float* wrow, float s) {
    float4 w0 = *(const float4*)(wrow);
    float4 w1 = *(const float4*)(wrow + 4);
    uint4 uu;
    uu.x = cvtpk(w0.x*s, w0.y*s); uu.y = cvtpk(w0.z*s, w0.w*s);
    uu.z = cvtpk(w1.x*s, w1.y*s); uu.w = cvtpk(w1.z*s, w1.w*s);
    union { uint4 u; short8 s8; } cv; cv.u = uu; return cv.s8;
}
__device__ __forceinline__ short8 packrow(const float* wrow) {
    return packrow_scaled(wrow, 1.0f);
}
// barrier draining LDS ops only; global prefetches stay in flight
__device__ __forceinline__ void lds_barrier() {
    asm volatile("s_waitcnt lgkmcnt(0)\n\ts_barrier" ::: "memory");
}

// ---------------- Kernel 1: F[b][n][g] = relu(bn(Wf @ feats[:,n])), bf16 ----
__global__ __launch_bounds__(256) void k_feats(
    const float* __restrict__ feats, const float* __restrict__ Wf,
    const float* __restrict__ bfv, const float* __restrict__ gf,
    const float* __restrict__ betaf, const float* __restrict__ mf,
    const float* __restrict__ vf, u16* __restrict__ Fout)
{
    __shared__ u16 A_lds[32][136];
    __shared__ u16 O_lds[32][136];
    const int t  = threadIdx.x;
    const int b  = blockIdx.x / NT32;
    const int n0 = (blockIdx.x % NT32) * 32;

    {
        const int chunk = t & 7;
        const int cbase = t >> 3;
        const float* base = feats + (size_t)b*CH*NPT + n0 + chunk*4;
        #pragma unroll
        for (int it = 0; it < 4; ++it) {
            int c = it*32 + cbase;
            float4 v = *(const float4*)(base + (size_t)c*NPT);
            A_lds[chunk*4+0][c] = f2bf1(v.x);
            A_lds[chunk*4+1][c] = f2bf1(v.y);
            A_lds[chunk*4+2][c] = f2bf1(v.z);
            A_lds[chunk*4+3][c] = f2bf1(v.w);
        }
    }

    const int lane = t & 63, wid = t >> 6;
    const int h = lane >> 4, r16 = lane & 15;
    const int gb = wid * 32;

    short8 bfrag[2][4];
    float sf[2], tf[2];
    #pragma unroll
    for (int T = 0; T < 2; ++T) {
        int g = gb + T*16 + r16;
        #pragma unroll
        for (int s = 0; s < 4; ++s)
            bfrag[T][s] = packrow(Wf + g*CH + s*32 + h*8);
        float inv = gf[g] * rsqrtf(vf[g] + EPSV);
        sf[T] = inv;
        tf[T] = bfv[g]*inv + betaf[g] - mf[g]*inv;
    }
    lds_barrier();

    #pragma unroll
    for (int sub = 0; sub < 2; ++sub) {
        short8 a[4];
        #pragma unroll
        for (int s = 0; s < 4; ++s)
            a[s] = *(const short8*)&A_lds[sub*16 + r16][s*32 + h*8];
        #pragma unroll
        for (int T = 0; T < 2; ++T) {
            f32x4 acc = {0.f, 0.f, 0.f, 0.f};
            #pragma unroll
            for (int s = 0; s < 4; ++s)
                acc = __builtin_amdgcn_mfma_f32_16x16x32_bf16(a[s], bfrag[T][s], acc, 0, 0, 0);
            #pragma unroll
            for (int r = 0; r < 4; ++r) {
                float y = fmaxf(fmaf(sf[T], acc[r], tf[T]), 0.f);
                O_lds[sub*16 + 4*h + r][gb + T*16 + r16] = f2bf1(y);
            }
        }
    }
    lds_barrier();

    {
        const int pp = t >> 3, cc = (t & 7) * 16;
        uint4 v0 = *(const uint4*)&O_lds[pp][cc];
        uint4 v1 = *(const uint4*)&O_lds[pp][cc + 8];
        u16* dst = Fout + ((size_t)b*NPT + n0 + pp)*CH + cc;
        *(uint4*)dst = v0;
        *(uint4*)(dst + 8) = v1;
    }
}

// ---- Kernel 2: 16-pt blocks, 2-plane chunks, pk-asm stage, lgkm barriers --
struct Pref { float4 m; uint4 f; };

__global__ __launch_bounds__(256) void k_main(
    const float* __restrict__ pts, const int* __restrict__ knn,
    const u16* __restrict__ F,
    const float* __restrict__ Wd, const float* __restrict__ bd,
    const float* __restrict__ gd, const float* __restrict__ betad,
    const float* __restrict__ md, const float* __restrict__ vd,
    const float* __restrict__ Wp, const float* __restrict__ bp,
    const float* __restrict__ gp, const float* __restrict__ betap,
    const float* __restrict__ mp, const float* __restrict__ vp,
    float* __restrict__ out)
{
    __shared__ u16    Abuf[2][2][16*128];   // 16 KB: [buf][plane], XOR-swizzled
    __shared__ float4 metaL[KNN][16];       // 4.35 KB: [k][row] {dx,dy,dz,byteoff}

    const int t  = threadIdx.x;
    const int b  = blockIdx.x / NT16;
    const int n0 = (blockIdx.x % NT16) * 16;

    const float* px = pts + (size_t)b*3*NPT;
    const float* py = px + NPT;
    const float* pz = py + NPT;

    // meta fill: 272 entries, plane-major [k][row]
    {
        const int* krow = knn + ((size_t)b*NPT + n0)*KNN;
        #pragma unroll 1
        for (int e = t; e < KNN*16; e += 256) {
            int k = e >> 4, p = e & 15;
            int nb = krow[p*KNN + k];
            float4 m;
            m.x = px[nb] - px[n0+p];
            m.y = py[nb] - py[n0+p];
            m.z = pz[nb] - pz[n0+p];
            m.w = __int_as_float(nb << 8);          // byte offset (256 B/row)
            metaL[k][p] = m;
        }
    }
    lds_barrier();                                  // meta visible to all waves

    const int p_t = t >> 4, j_t = t & 15, c0 = j_t*8;
    const int lane = t & 63, wid = t >> 6;
    const int h = lane >> 4, r16 = lane & 15;
    const int gb = wid * 32;
    const char* FbjB = (const char*)(F + (size_t)b*NPT*CH + c0);

    const int wOff = p_t*128 + (c0 ^ ((p_t&7)*8));
    int rOff[4];
    #pragma unroll
    for (int s = 0; s < 4; ++s)
        rOff[s] = r16*128 + ((s*32 + h*8) ^ ((r16&7)*8));

    auto issueK = [&](int k)->Pref {
        Pref P;
        P.m = metaL[k][p_t];
        P.f = *(const uint4*)(FbjB + __float_as_int(P.m.w));
        return P;
    };

    // 4-plane register prefetch queue (no copies: PA/PB refilled alternately)
    Pref PA0 = issueK(0), PA1 = issueK(1);
    Pref PB0 = issueK(2), PB1 = issueK(3);

    // B fragments (scale folded) + BN offsets — long VALU stretch hides gathers
    short8 bfrag[2][4];
    float tpv[2];
    #pragma unroll
    for (int T = 0; T < 2; ++T) {
        int g = gb + T*16 + r16;
        float inv = gp[g] * rsqrtf(vp[g] + EPSV);
        #pragma unroll
        for (int s = 0; s < 4; ++s)
            bfrag[T][s] = packrow_scaled(Wp + g*CH + s*32 + h*8, inv);
        tpv[T] = bp[g]*inv + betap[g] - mp[g]*inv;
    }

    f32x2 wx2[4], wy2[4], wz2[4], t2[4];
    #pragma unroll
    for (int q = 0; q < 4; ++q) {
        const int ca = c0 + 2*q, cb = ca + 1;
        float inva = gd[ca] * rsqrtf(vd[ca] + EPSV);
        float invb = gd[cb] * rsqrtf(vd[cb] + EPSV);
        wx2[q][0] = Wd[ca*3+0]*inva; wx2[q][1] = Wd[cb*3+0]*invb;
        wy2[q][0] = Wd[ca*3+1]*inva; wy2[q][1] = Wd[cb*3+1]*invb;
        wz2[q][0] = Wd[ca*3+2]*inva; wz2[q][1] = Wd[cb*3+2]*invb;
        t2[q][0]  = bd[ca]*inva + betad[ca] - md[ca]*inva;
        t2[q][1]  = bd[cb]*invb + betad[cb] - md[cb]*invb;
    }

    auto stage = [&](u16* plane, const Pref& Pr) {
        const unsigned fw[4] = {Pr.f.x, Pr.f.y, Pr.f.z, Pr.f.w};
        const f32x2 z2 = {0.f, 0.f};
        f32x2 dx2 = {Pr.m.x, Pr.m.x}, dy2 = {Pr.m.y, Pr.m.y}, dz2 = {Pr.m.z, Pr.m.z};
        unsigned pk[4];
        #pragma unroll
        for (int q = 0; q < 4; ++q) {
            f32x2 d = pk_fma(wx2[q], dx2, pk_fma(wy2[q], dy2, pk_fma(wz2[q], dz2, t2[q])));
            d = __builtin_elementwise_max(d, z2);
            f32x2 pr = pk_mul(d, bfpair(fw[q]));
            pk[q] = cvtpk(pr[0], pr[1]);
        }
        uint4 v; v.x = pk[0]; v.y = pk[1]; v.z = pk[2]; v.w = pk[3];
        *(uint4*)(plane + wOff) = v;
    };

    f32x4 facc[2] = {};
    auto mfmaP = [&](const u16* plane) {
        short8 a[4];
        #pragma unroll
        for (int s = 0; s < 4; ++s)
            a[s] = *(const short8*)(plane + rOff[s]);
        #pragma unroll
        for (int T = 0; T < 2; ++T) {
            f32x4 acc = {0.f,0.f,0.f,0.f};
            #pragma unroll
            for (int s = 0; s < 4; ++s)
                acc = __builtin_amdgcn_mfma_f32_16x16x32_bf16(a[s], bfrag[T][s], acc, 0, 0, 0);
            f32x4 nt = {-tpv[T], -tpv[T], -tpv[T], -tpv[T]};
            facc[T] += __builtin_elementwise_max(acc, nt);
        }
    };

    u16* B0 = &Abuf[0][0][0];
    u16* B1 = &Abuf[1][0][0];

    // chunk body: stage 2 planes into sb, refill queue, mfma 2 planes from mb
    auto chunk = [&](u16* sb, const u16* mb, Pref& S0, Pref& S1, int r0, int r1) {
        stage(sb, S0);
        stage(sb + 2048, S1);
        if (r0 >= 0) S0 = issueK(r0);
        if (r1 >= 0) S1 = issueK(r1);
        mfmaP(mb);
        mfmaP(mb + 2048);
        lds_barrier();
    };

    // prologue: stage planes 0,1 -> B0; refill PA with 4,5
    stage(B0, PA0);
    stage(B0 + 2048, PA1);
    PA0 = issueK(4); PA1 = issueK(5);
    lds_barrier();

    chunk(B1, B0, PB0, PB1,  6,  7);   // mfma 0,1   stage 2,3
    chunk(B0, B1, PA0, PA1,  8,  9);   // mfma 2,3   stage 4,5
    chunk(B1, B0, PB0, PB1, 10, 11);   // mfma 4,5   stage 6,7
    chunk(B0, B1, PA0, PA1, 12, 13);   // mfma 6,7   stage 8,9
    chunk(B1, B0, PB0, PB1, 14, 15);   // mfma 8,9   stage 10,11
    chunk(B0, B1, PA0, PA1, 16, -1);   // mfma 10,11 stage 12,13
    chunk(B1, B0, PB0, PB1, -1, -1);   // mfma 12,13 stage 14,15

    // tail: stage plane 16, mfma 14,15, then 16
    stage(B0, PA0);
    mfmaP(B1);
    mfmaP(B1 + 2048);
    lds_barrier();
    mfmaP(B0);

    #pragma unroll
    for (int T = 0; T < 2; ++T) {
        int g = gb + T*16 + r16;
        f32x4 o = facc[T] + (float)KNN * tpv[T];
        *(f32x4*)(out + ((size_t)b*CH + g)*NPT + n0 + 4*h) = o;
    }
}

extern "C" void kernel_launch(void* const* d_in, const int* in_sizes, int n_in,
                              void* d_out, int out_size, void* d_ws, size_t ws_size,
                              hipStream_t stream)
{
    const float* feats = (const float*)d_in[0];
    const float* pts   = (const float*)d_in[1];
    const int*   knn   = (const int*)d_in[2];
    const float* Wd    = (const float*)d_in[3];
    const float* bd    = (const float*)d_in[4];
    const float* gd    = (const float*)d_in[5];
    const float* betad = (const float*)d_in[6];
    const float* md    = (const float*)d_in[7];
    const float* vd    = (const float*)d_in[8];
    const float* Wf    = (const float*)d_in[9];
    const float* bfv   = (const float*)d_in[10];
    const float* gf    = (const float*)d_in[11];
    const float* betaf = (const float*)d_in[12];
    const float* mf    = (const float*)d_in[13];
    const float* vf    = (const float*)d_in[14];
    const float* Wp    = (const float*)d_in[15];
    const float* bp    = (const float*)d_in[16];
    const float* gp    = (const float*)d_in[17];
    const float* betap = (const float*)d_in[18];
    const float* mp    = (const float*)d_in[19];
    const float* vp    = (const float*)d_in[20];
    float* out = (float*)d_out;
    u16* Fws = (u16*)d_ws;   // B*N*128 bf16 = 10.24 MB

    k_feats<<<dim3(NB * NT32), 256, 0, stream>>>(feats, Wf, bfv, gf, betaf, mf, vf, Fws);
    k_main <<<dim3(NB * NT16), 256, 0, stream>>>(pts, knn, Fws, Wd, bd, gd, betad, md, vd,
                                                 Wp, bp, gp, betap, mp, vp, out);
}

// Round 10
// 75.960 us; speedup vs baseline: 1.0854x; 1.0854x over previous
//
#include <hip/hip_runtime.h>
#include <hip/hip_bf16.h>
#include <cstdint>
#include <cstddef>

#define NB 2
#define NPT 20000
#define KNN 17
#define CH 128
#define NT16 (NPT/16)
#define NT32 (NPT/32)
#define EPSV 1e-5f

typedef short short8 __attribute__((ext_vector_type(8)));
typedef float f32x4 __attribute__((ext_vector_type(4)));
typedef float f32x2 __attribute__((ext_vector_type(2)));
typedef unsigned short u16;

__device__ __forceinline__ unsigned cvtpk(float lo, float hi) {
    unsigned r;
    asm("v_cvt_pk_bf16_f32 %0, %1, %2" : "=v"(r) : "v"(lo), "v"(hi));
    return r;
}
__device__ __forceinline__ u16 f2bf1(float x) { return (u16)cvtpk(x, x); }
__device__ __forceinline__ f32x2 pk_fma(f32x2 a, f32x2 b, f32x2 c) {
    f32x2 d;
    asm("v_pk_fma_f32 %0, %1, %2, %3" : "=v"(d) : "v"(a), "v"(b), "v"(c));
    return d;
}
__device__ __forceinline__ f32x2 pk_mul(f32x2 a, f32x2 b) {
    f32x2 d;
    asm("v_pk_mul_f32 %0, %1, %2" : "=v"(d) : "v"(a), "v"(b));
    return d;
}
__device__ __forceinline__ f32x2 bfpair(unsigned w) {
    union { unsigned u; float f; } lo, hi;
    lo.u = w << 16; hi.u = w & 0xffff0000u;
    f32x2 r; r[0] = lo.f; r[1] = hi.f; return r;
}
__device__ __forceinline__ short8 packrow_scaled(const float* wrow, float s) {
    float4 w0 = *(const float4*)(wrow);
    float4 w1 = *(const float4*)(wrow + 4);
    uint4 uu;
    uu.x = cvtpk(w0.x*s, w0.y*s); uu.y = cvtpk(w0.z*s, w0.w*s);
    uu.z = cvtpk(w1.x*s, w1.y*s); uu.w = cvtpk(w1.z*s, w1.w*s);
    union { uint4 u; short8 s8; } cv; cv.u = uu; return cv.s8;
}
__device__ __forceinline__ short8 packrow(const float* wrow) {
    return packrow_scaled(wrow, 1.0f);
}
// barrier draining LDS ops only; global prefetches stay in flight
__device__ __forceinline__ void lds_barrier() {
    asm volatile("s_waitcnt lgkmcnt(0)\n\ts_barrier" ::: "memory");
}

// ---------------- Kernel 1: F[b][n][g] = relu(bn(Wf @ feats[:,n])), bf16 ----
__global__ __launch_bounds__(256) void k_feats(
    const float* __restrict__ feats, const float* __restrict__ Wf,
    const float* __restrict__ bfv, const float* __restrict__ gf,
    const float* __restrict__ betaf, const float* __restrict__ mf,
    const float* __restrict__ vf, u16* __restrict__ Fout)
{
    __shared__ u16 A_lds[32][136];
    __shared__ u16 O_lds[32][136];
    const int t  = threadIdx.x;
    const int b  = blockIdx.x / NT32;
    const int n0 = (blockIdx.x % NT32) * 32;

    {
        const int chunk = t & 7;
        const int cbase = t >> 3;
        const float* base = feats + (size_t)b*CH*NPT + n0 + chunk*4;
        #pragma unroll
        for (int it = 0; it < 4; ++it) {
            int c = it*32 + cbase;
            float4 v = *(const float4*)(base + (size_t)c*NPT);
            A_lds[chunk*4+0][c] = f2bf1(v.x);
            A_lds[chunk*4+1][c] = f2bf1(v.y);
            A_lds[chunk*4+2][c] = f2bf1(v.z);
            A_lds[chunk*4+3][c] = f2bf1(v.w);
        }
    }

    const int lane = t & 63, wid = t >> 6;
    const int h = lane >> 4, r16 = lane & 15;
    const int gb = wid * 32;

    short8 bfrag[2][4];
    float sf[2], tf[2];
    #pragma unroll
    for (int T = 0; T < 2; ++T) {
        int g = gb + T*16 + r16;
        #pragma unroll
        for (int s = 0; s < 4; ++s)
            bfrag[T][s] = packrow(Wf + g*CH + s*32 + h*8);
        float inv = gf[g] * rsqrtf(vf[g] + EPSV);
        sf[T] = inv;
        tf[T] = bfv[g]*inv + betaf[g] - mf[g]*inv;
    }
    lds_barrier();

    #pragma unroll
    for (int sub = 0; sub < 2; ++sub) {
        short8 a[4];
        #pragma unroll
        for (int s = 0; s < 4; ++s)
            a[s] = *(const short8*)&A_lds[sub*16 + r16][s*32 + h*8];
        #pragma unroll
        for (int T = 0; T < 2; ++T) {
            f32x4 acc = {0.f, 0.f, 0.f, 0.f};
            #pragma unroll
            for (int s = 0; s < 4; ++s)
                acc = __builtin_amdgcn_mfma_f32_16x16x32_bf16(a[s], bfrag[T][s], acc, 0, 0, 0);
            #pragma unroll
            for (int r = 0; r < 4; ++r) {
                float y = fmaxf(fmaf(sf[T], acc[r], tf[T]), 0.f);
                O_lds[sub*16 + 4*h + r][gb + T*16 + r16] = f2bf1(y);
            }
        }
    }
    lds_barrier();

    {
        const int pp = t >> 3, cc = (t & 7) * 16;
        uint4 v0 = *(const uint4*)&O_lds[pp][cc];
        uint4 v1 = *(const uint4*)&O_lds[pp][cc + 8];
        u16* dst = Fout + ((size_t)b*NPT + n0 + pp)*CH + cc;
        *(uint4*)dst = v0;
        *(uint4*)(dst + 8) = v1;
    }
}

// ---- Kernel 2: TWO-PHASE — stage all 17 planes, ONE barrier, MFMA burst ---
struct Pref { float4 m; uint4 f; };

__global__ __launch_bounds__(256) void k_main(
    const float* __restrict__ pts, const int* __restrict__ knn,
    const u16* __restrict__ F,
    const float* __restrict__ Wd, const float* __restrict__ bd,
    const float* __restrict__ gd, const float* __restrict__ betad,
    const float* __restrict__ md, const float* __restrict__ vd,
    const float* __restrict__ Wp, const float* __restrict__ bp,
    const float* __restrict__ gp, const float* __restrict__ betap,
    const float* __restrict__ mp, const float* __restrict__ vp,
    float* __restrict__ out)
{
    __shared__ u16    Apl[KNN*2048];        // 69.6 KB: 17 planes, XOR-swizzled
    __shared__ float4 metaL[KNN][16];       // 4.35 KB: [k][row] {dx,dy,dz,byteoff}

    const int t  = threadIdx.x;
    const int b  = blockIdx.x / NT16;
    const int n0 = (blockIdx.x % NT16) * 16;

    const float* px = pts + (size_t)b*3*NPT;
    const float* py = px + NPT;
    const float* pz = py + NPT;

    // meta fill: 272 entries, plane-major [k][row]
    {
        const int* krow = knn + ((size_t)b*NPT + n0)*KNN;
        #pragma unroll 1
        for (int e = t; e < KNN*16; e += 256) {
            int k = e >> 4, p = e & 15;
            int nb = krow[p*KNN + k];
            float4 m;
            m.x = px[nb] - px[n0+p];
            m.y = py[nb] - py[n0+p];
            m.z = pz[nb] - pz[n0+p];
            m.w = __int_as_float(nb << 8);          // byte offset (256 B/row)
            metaL[k][p] = m;
        }
    }
    lds_barrier();                                  // meta visible to all waves

    const int p_t = t >> 4, j_t = t & 15, c0 = j_t*8;
    const int lane = t & 63, wid = t >> 6;
    const int h = lane >> 4, r16 = lane & 15;
    const int gb = wid * 32;
    const char* FbjB = (const char*)(F + (size_t)b*NPT*CH + c0);

    const int wOff = p_t*128 + (c0 ^ ((p_t&7)*8));
    int rOff[4];
    #pragma unroll
    for (int s = 0; s < 4; ++s)
        rOff[s] = r16*128 + ((s*32 + h*8) ^ ((r16&7)*8));

    auto issueK = [&](int k)->Pref {
        Pref P;
        P.m = metaL[k][p_t];
        P.f = *(const uint4*)(FbjB + __float_as_int(P.m.w));
        return P;
    };

    // 6-deep rotating gather queue, issued before the long prologue VALU
    Pref P0 = issueK(0), P1 = issueK(1), P2 = issueK(2),
         P3 = issueK(3), P4 = issueK(4), P5 = issueK(5);

    // B fragments (scale folded) + BN offsets — hides the first gathers
    short8 bfrag[2][4];
    float tpv[2];
    #pragma unroll
    for (int T = 0; T < 2; ++T) {
        int g = gb + T*16 + r16;
        float inv = gp[g] * rsqrtf(vp[g] + EPSV);
        #pragma unroll
        for (int s = 0; s < 4; ++s)
            bfrag[T][s] = packrow_scaled(Wp + g*CH + s*32 + h*8, inv);
        tpv[T] = bp[g]*inv + betap[g] - mp[g]*inv;
    }

    f32x2 wx2[4], wy2[4], wz2[4], t2[4];
    #pragma unroll
    for (int q = 0; q < 4; ++q) {
        const int ca = c0 + 2*q, cb = ca + 1;
        float inva = gd[ca] * rsqrtf(vd[ca] + EPSV);
        float invb = gd[cb] * rsqrtf(vd[cb] + EPSV);
        wx2[q][0] = Wd[ca*3+0]*inva; wx2[q][1] = Wd[cb*3+0]*invb;
        wy2[q][0] = Wd[ca*3+1]*inva; wy2[q][1] = Wd[cb*3+1]*invb;
        wz2[q][0] = Wd[ca*3+2]*inva; wz2[q][1] = Wd[cb*3+2]*invb;
        t2[q][0]  = bd[ca]*inva + betad[ca] - md[ca]*inva;
        t2[q][1]  = bd[cb]*invb + betad[cb] - md[cb]*invb;
    }

    auto stage = [&](u16* plane, const Pref& Pr) {
        const unsigned fw[4] = {Pr.f.x, Pr.f.y, Pr.f.z, Pr.f.w};
        const f32x2 z2 = {0.f, 0.f};
        f32x2 dx2 = {Pr.m.x, Pr.m.x}, dy2 = {Pr.m.y, Pr.m.y}, dz2 = {Pr.m.z, Pr.m.z};
        unsigned pk[4];
        #pragma unroll
        for (int q = 0; q < 4; ++q) {
            f32x2 d = pk_fma(wx2[q], dx2, pk_fma(wy2[q], dy2, pk_fma(wz2[q], dz2, t2[q])));
            d = __builtin_elementwise_max(d, z2);
            f32x2 pr = pk_mul(d, bfpair(fw[q]));
            pk[q] = cvtpk(pr[0], pr[1]);
        }
        uint4 v; v.x = pk[0]; v.y = pk[1]; v.z = pk[2]; v.w = pk[3];
        *(uint4*)(plane + wOff) = v;
    };

    // -------- phase 1: stage planes 0..16, no barriers (disjoint LDS) ------
    auto stepk = [&](int k, Pref& Pr, int knext) {
        stage(Apl + k*2048, Pr);
        if (knext < KNN) Pr = issueK(knext);
    };
    stepk( 0, P0,  6); stepk( 1, P1,  7); stepk( 2, P2,  8);
    stepk( 3, P3,  9); stepk( 4, P4, 10); stepk( 5, P5, 11);
    stepk( 6, P0, 12); stepk( 7, P1, 13); stepk( 8, P2, 14);
    stepk( 9, P3, 15); stepk(10, P4, 16); stepk(11, P5, 99);
    stepk(12, P0, 99); stepk(13, P1, 99); stepk(14, P2, 99);
    stepk(15, P3, 99); stepk(16, P4, 99);

    lds_barrier();                           // the ONE produce->consume sync

    // -------- phase 2: pure MFMA burst, A-frags double-buffered ------------
    f32x4 facc[2] = {};
    short8 aA[4], aB[4];
    auto LDA = [&](short8* a, int k) {
        const u16* pl = Apl + k*2048;
        #pragma unroll
        for (int s = 0; s < 4; ++s)
            a[s] = *(const short8*)(pl + rOff[s]);
    };
    auto MFMA8 = [&](const short8* a) {
        #pragma unroll
        for (int T = 0; T < 2; ++T) {
            f32x4 acc = {0.f,0.f,0.f,0.f};
            #pragma unroll
            for (int s = 0; s < 4; ++s)
                acc = __builtin_amdgcn_mfma_f32_16x16x32_bf16(a[s], bfrag[T][s], acc, 0, 0, 0);
            f32x4 nt = {-tpv[T], -tpv[T], -tpv[T], -tpv[T]};
            facc[T] += __builtin_elementwise_max(acc, nt);
        }
    };

    LDA(aA, 0);
    #pragma unroll
    for (int i = 0; i < 8; ++i) {
        LDA(aB, 2*i + 1);
        MFMA8(aA);                           // plane 2i
        LDA(aA, 2*i + 2);                    // i=7 loads plane 16
        MFMA8(aB);                           // plane 2i+1
    }
    MFMA8(aA);                               // plane 16

    #pragma unroll
    for (int T = 0; T < 2; ++T) {
        int g = gb + T*16 + r16;
        f32x4 o = facc[T] + (float)KNN * tpv[T];
        *(f32x4*)(out + ((size_t)b*CH + g)*NPT + n0 + 4*h) = o;
    }
}

extern "C" void kernel_launch(void* const* d_in, const int* in_sizes, int n_in,
                              void* d_out, int out_size, void* d_ws, size_t ws_size,
                              hipStream_t stream)
{
    const float* feats = (const float*)d_in[0];
    const float* pts   = (const float*)d_in[1];
    const int*   knn   = (const int*)d_in[2];
    const float* Wd    = (const float*)d_in[3];
    const float* bd    = (const float*)d_in[4];
    const float* gd    = (const float*)d_in[5];
    const float* betad = (const float*)d_in[6];
    const float* md    = (const float*)d_in[7];
    const float* vd    = (const float*)d_in[8];
    const float* Wf    = (const float*)d_in[9];
    const float* bfv   = (const float*)d_in[10];
    const float* gf    = (const float*)d_in[11];
    const float* betaf = (const float*)d_in[12];
    const float* mf    = (const float*)d_in[13];
    const float* vf    = (const float*)d_in[14];
    const float* Wp    = (const float*)d_in[15];
    const float* bp    = (const float*)d_in[16];
    const float* gp    = (const float*)d_in[17];
    const float* betap = (const float*)d_in[18];
    const float* mp    = (const float*)d_in[19];
    const float* vp    = (const float*)d_in[20];
    float* out = (float*)d_out;
    u16* Fws = (u16*)d_ws;   // B*N*128 bf16 = 10.24 MB

    k_feats<<<dim3(NB * NT32), 256, 0, stream>>>(feats, Wf, bfv, gf, betaf, mf, vf, Fws);
    k_main <<<dim3(NB * NT16), 256, 0, stream>>>(pts, knn, Fws, Wd, bd, gd, betad, md, vd,
                                                 Wp, bp, gp, betap, mp, vp, out);
}